// Round 7
// baseline (1051.920 us; speedup 1.0000x reference)
//
#include <hip/hip_runtime.h>
#include <math.h>

#define N_NODES 100000
#define N_EDGES 1600000
#define UNITS   256
#define NGRAPH  512
#define IN_FEAT 9
#define NB_SCAN ((N_NODES + 255) / 256)   // 391

typedef short bf16x8 __attribute__((ext_vector_type(8)));
typedef float f32x4  __attribute__((ext_vector_type(4)));

__device__ __forceinline__ float bflo(unsigned int u) {
  return __builtin_bit_cast(float, u << 16);
}
__device__ __forceinline__ float bfhi(unsigned int u) {
  return __builtin_bit_cast(float, u & 0xffff0000u);
}
__device__ __forceinline__ unsigned short f2bf(float f) {
  unsigned int u = __builtin_bit_cast(unsigned int, f);
  u += 0x7fffu + ((u >> 16) & 1u);   // round-to-nearest-even
  return (unsigned short)(u >> 16);
}

// byte offset into a [rows][64] bf16 LDS tile (128 B rows) with T2 XOR swizzle
__device__ __forceinline__ int swz(int row, int byteInRow) {
  return row * 128 + (byteInRow ^ ((row & 7) << 4));
}

// async global->LDS, 16B per lane; LDS dest = uniform base + lane*16 (HW)
__device__ __forceinline__ void gload_lds16(const void* g, void* l) {
  __builtin_amdgcn_global_load_lds(
      (const __attribute__((address_space(1))) unsigned int*)g,
      (__attribute__((address_space(3))) unsigned int*)l, 16, 0, 0);
}

// ============================ CSR build ============================

__global__ void k_count(const int* __restrict__ ei, int* __restrict__ cnt) {
  int e = blockIdx.x * blockDim.x + threadIdx.x;
  if (e < N_EDGES) atomicAdd(&cnt[ei[N_EDGES + e]], 1);
}

// hierarchical scan: per-256-block sums
__global__ __launch_bounds__(256) void k_bsum(const int* __restrict__ cnt,
                                              int* __restrict__ bsum) {
  __shared__ int wsS[4];
  int b = blockIdx.x, tid = threadIdx.x, lane = tid & 63, w = tid >> 6;
  int idx = b * 256 + tid;
  int s = (idx < N_NODES) ? cnt[idx] : 0;
  #pragma unroll
  for (int m = 32; m >= 1; m >>= 1) s += __shfl_xor(s, m);
  if (lane == 0) wsS[w] = s;
  __syncthreads();
  if (tid == 0) bsum[b] = wsS[0] + wsS[1] + wsS[2] + wsS[3];
}

// exclusive scan of the NB_SCAN block sums (single 512-thread block)
__global__ __launch_bounds__(512) void k_bscan(int* __restrict__ bsum) {
  __shared__ int wsS[8];
  int tid = threadIdx.x, lane = tid & 63, w = tid >> 6;
  int v = (tid < NB_SCAN) ? bsum[tid] : 0;
  int s = v;
  #pragma unroll
  for (int off = 1; off < 64; off <<= 1) {
    int t = __shfl_up(s, off);
    if (lane >= off) s += t;
  }
  if (lane == 63) wsS[w] = s;
  __syncthreads();
  int woff = 0;
  #pragma unroll
  for (int i = 0; i < 8; ++i) woff += (i < w) ? wsS[i] : 0;
  if (tid < NB_SCAN) bsum[tid] = woff + s - v;   // exclusive
}

// block-local exclusive scan + global offset -> row_ptr
__global__ __launch_bounds__(256) void k_scan3(const int* __restrict__ cnt,
                                               const int* __restrict__ bsum,
                                               int* __restrict__ row_ptr) {
  __shared__ int wsS[4];
  int b = blockIdx.x, tid = threadIdx.x, lane = tid & 63, w = tid >> 6;
  int idx = b * 256 + tid;
  int v = (idx < N_NODES) ? cnt[idx] : 0;
  int s = v;
  #pragma unroll
  for (int off = 1; off < 64; off <<= 1) {
    int t = __shfl_up(s, off);
    if (lane >= off) s += t;
  }
  if (lane == 63) wsS[w] = s;
  __syncthreads();
  int woff = 0;
  #pragma unroll
  for (int i = 0; i < 4; ++i) woff += (i < w) ? wsS[i] : 0;
  if (idx < N_NODES) row_ptr[idx] = bsum[b] + woff + s - v;
  if (idx == 0) row_ptr[N_NODES] = N_EDGES;
}

__global__ void k_dinv(const int* __restrict__ cnt, float* __restrict__ dinv) {
  int n = blockIdx.x * blockDim.x + threadIdx.x;
  if (n < N_NODES) dinv[n] = rsqrtf((float)cnt[n] + 1.0f);  // +1 self-loop
}

__global__ void k_fill(const int* __restrict__ ei, const int* __restrict__ row_ptr,
                       int* __restrict__ fill, int* __restrict__ col) {
  int e = blockIdx.x * blockDim.x + threadIdx.x;
  if (e < N_EDGES) {
    int s = ei[e];
    int d = ei[N_EDGES + e];
    int pos = row_ptr[d] + atomicAdd(&fill[d], 1);
    col[pos] = s;
  }
}

// segment starts: starts[g] = lower_bound(batch, g); starts[NGRAPH] = N_NODES
__global__ void k_bounds(const int* __restrict__ batch, int* __restrict__ starts) {
  int g = blockIdx.x * blockDim.x + threadIdx.x;
  if (g > NGRAPH) return;
  if (g == NGRAPH) { starts[g] = N_NODES; return; }
  int lo = 0, hi = N_NODES;
  while (lo < hi) { int m = (lo + hi) >> 1; if (batch[m] < g) lo = m + 1; else hi = m; }
  starts[g] = lo;
}

// ============================ Weight transpose/convert ============================

// Wt[m][n][k] = W_m[k][n] as bf16; m = 0..2 -> Ws, m = 3 -> fc1_w
__global__ void k_cvtW(const float* __restrict__ Ws, const float* __restrict__ fc1_w,
                       unsigned short* __restrict__ Wt) {
  int idx = blockIdx.x * 256 + threadIdx.x;   // < 4*256*256
  int m = idx >> 16;
  int r = idx & 65535;
  int n = r >> 8;
  int k = r & 255;
  const float* src = (m < 3) ? (Ws + (size_t)m * 65536) : fc1_w;
  Wt[idx] = f2bf(src[k * 256 + n]);
}

// Wt2[n][k] = fc2_w[k][n] as bf16 (32x256)
__global__ void k_cvtW2(const float* __restrict__ fc2_w, unsigned short* __restrict__ Wt2) {
  int idx = blockIdx.x * 256 + threadIdx.x;   // < 32*256
  int n = idx >> 8;
  int k = idx & 255;
  Wt2[idx] = f2bf(fc2_w[k * 32 + n]);
}

// xs = dinv (x) x  (pre-scaled input features, f32)
__global__ void k_scalex(const float* __restrict__ x, const float* __restrict__ dinv,
                         float* __restrict__ xs) {
  int idx = blockIdx.x * blockDim.x + threadIdx.x;
  if (idx < N_NODES * IN_FEAT) xs[idx] = x[idx] * dinv[idx / IN_FEAT];
}

// ============================ Aggregation ============================

// p0 = dn * (xs[n] + sum xs[src])   (9 features, f32, thread per node)
__global__ void k_agg9(const float* __restrict__ xs, const int* __restrict__ row_ptr,
                       const int* __restrict__ col, const float* __restrict__ dinv,
                       float* __restrict__ p0) {
  int n = blockIdx.x * blockDim.x + threadIdx.x;
  if (n >= N_NODES) return;
  float acc[IN_FEAT];
  #pragma unroll
  for (int j = 0; j < IN_FEAT; ++j) acc[j] = xs[n * IN_FEAT + j];
  int beg = row_ptr[n], end = row_ptr[n + 1];
  for (int e = beg; e < end; ++e) {
    int s = col[e];
    #pragma unroll
    for (int j = 0; j < IN_FEAT; ++j) acc[j] += xs[s * IN_FEAT + j];
  }
  float dn = dinv[n];
  #pragma unroll
  for (int j = 0; j < IN_FEAT; ++j) p0[n * IN_FEAT + j] = dn * acc[j];
}

// p = dn * (hs[n] + sum hs[src])  (hs pre-scaled by dinv; pure gather+add)
__global__ __launch_bounds__(256) void k_agg256(
    const unsigned short* __restrict__ hs, const int* __restrict__ row_ptr,
    const int* __restrict__ col, const float* __restrict__ dinv,
    unsigned short* __restrict__ p) {
  int wid = threadIdx.x >> 6;
  int lane = threadIdx.x & 63;
  int n = blockIdx.x * 4 + wid;
  if (n >= N_NODES) return;
  uint2 q = *(const uint2*)(hs + (size_t)n * UNITS + lane * 4);
  float a0 = bflo(q.x), a1 = bfhi(q.x);
  float a2 = bflo(q.y), a3 = bfhi(q.y);
  int e = row_ptr[n], end = row_ptr[n + 1];
  for (; e + 8 <= end; e += 8) {          // 8 gathers in flight
    int s[8];
    uint2 qq[8];
    #pragma unroll
    for (int j = 0; j < 8; ++j) s[j] = col[e + j];
    #pragma unroll
    for (int j = 0; j < 8; ++j)
      qq[j] = *(const uint2*)(hs + (size_t)s[j] * UNITS + lane * 4);
    #pragma unroll
    for (int j = 0; j < 8; ++j) {
      a0 += bflo(qq[j].x); a1 += bfhi(qq[j].x);
      a2 += bflo(qq[j].y); a3 += bfhi(qq[j].y);
    }
  }
  if (e + 4 <= end) {
    int s[4];
    uint2 qq[4];
    #pragma unroll
    for (int j = 0; j < 4; ++j) s[j] = col[e + j];
    #pragma unroll
    for (int j = 0; j < 4; ++j)
      qq[j] = *(const uint2*)(hs + (size_t)s[j] * UNITS + lane * 4);
    #pragma unroll
    for (int j = 0; j < 4; ++j) {
      a0 += bflo(qq[j].x); a1 += bfhi(qq[j].x);
      a2 += bflo(qq[j].y); a3 += bfhi(qq[j].y);
    }
    e += 4;
  }
  for (; e < end; ++e) {
    int s0 = col[e];
    uint2 q0 = *(const uint2*)(hs + (size_t)s0 * UNITS + lane * 4);
    a0 += bflo(q0.x); a1 += bfhi(q0.x);
    a2 += bflo(q0.y); a3 += bfhi(q0.y);
  }
  float dn = dinv[n];
  uint2 o;
  o.x = (unsigned int)f2bf(dn * a0) | ((unsigned int)f2bf(dn * a1) << 16);
  o.y = (unsigned int)f2bf(dn * a2) | ((unsigned int)f2bf(dn * a3) << 16);
  *(uint2*)(p + (size_t)n * UNITS + lane * 4) = o;
}

// ============================ GEMMs ============================

// h = scale? * tanh(p0 @ Win + bin) -> bf16   [N,9] x [9,256]
__global__ __launch_bounds__(256) void k_gemm9(const float* __restrict__ p0,
                                               const float* __restrict__ Win,
                                               const float* __restrict__ bin,
                                               const float* __restrict__ scale,
                                               unsigned short* __restrict__ h) {
  __shared__ float pS[32][IN_FEAT];
  int tid = threadIdx.x;
  int row0 = blockIdx.x * 32;
  for (int i = tid; i < 32 * IN_FEAT; i += 256) {
    int r = i / IN_FEAT;
    pS[r][i % IN_FEAT] = (row0 + r < N_NODES) ? p0[(size_t)row0 * IN_FEAT + i] : 0.0f;
  }
  float wcol[IN_FEAT];
  #pragma unroll
  for (int k = 0; k < IN_FEAT; ++k) wcol[k] = Win[k * UNITS + tid];
  float b = bin[tid];
  __syncthreads();
  for (int r = 0; r < 32; ++r) {
    int gr = row0 + r;
    if (gr >= N_NODES) break;
    float a = b;
    #pragma unroll
    for (int k = 0; k < IN_FEAT; ++k) a += pS[r][k] * wcol[k];
    float sc = scale ? scale[gr] : 1.0f;
    h[(size_t)gr * UNITS + tid] = f2bf(sc * tanhf(a));
  }
}

// C = scale? * tanh(A @ W + bias) in bf16. A:[M][256], Wt:[256][256] (Wt[n][k]).
// m97 structure: global_load_lds staging (linear LDS dest, inverse-swizzled
// per-lane global source), single-buffered, 2 barriers per K-slice of 64.
// 4 waves 2x2; wave(wr,wc) owns rows 64wr..+63 x cols 128wc..+127.
__global__ __launch_bounds__(256, 3) void k_gemm_bf16(
    const unsigned short* __restrict__ A,
    const unsigned short* __restrict__ Wt,
    const float* __restrict__ bias,
    const float* __restrict__ scale,   // nullable: per-row output scaling (dinv)
    unsigned short* __restrict__ C,
    int M) {
  __shared__ __align__(16) char lds[49152];   // 48 KiB
  char* As = lds;                  // [128][64] bf16 swizzled-read, 16 KiB
  char* Bs = lds + 16384;          // [256][64] bf16 swizzled-read, 32 KiB
  unsigned short (*Cs)[264] = (unsigned short(*)[264])lds;  // epilogue repack (reused)

  const int tid = threadIdx.x;
  const int w = tid >> 6;
  const int l = tid & 63;
  const int l15 = l & 15;
  const int blk = l >> 4;
  const int wr = w >> 1;           // 0..1 row-group
  const int wc = w & 1;            // 0..1 col-group
  const int row0 = blockIdx.x * 128;

  const int lr = l >> 3;           // staging: row within 8-row group (0..7)
  const int lc = (l & 7) * 16;     // staging: 16B chunk byte in 128B row

  f32x4 acc[4][8];
  #pragma unroll
  for (int rf = 0; rf < 4; ++rf)
    #pragma unroll
    for (int cf = 0; cf < 8; ++cf) acc[rf][cf] = (f32x4){0.f, 0.f, 0.f, 0.f};

  for (int ks = 0; ks < 4; ++ks) {
    const int k0 = ks * 64;
    if (ks) __syncthreads();       // staging buffers free to overwrite
    // stage A slice [128][64]: 16 x 1KB wave-issues, 4 per wave
    #pragma unroll
    for (int i = 0; i < 4; ++i) {
      int rb = (w * 4 + i) * 8;                    // wave-uniform row base
      int r = rb + lr;
      int gr = row0 + r; if (gr >= M) gr = M - 1;
      const char* src = (const char*)A + (size_t)gr * 512 + k0 * 2
                        + (lc ^ ((r & 7) << 4));   // inverse swizzle on source
      int dstoff = __builtin_amdgcn_readfirstlane(rb * 128);
      gload_lds16(src, As + dstoff);               // HW adds lane*16
    }
    // stage B slice [256][64]: 32 x 1KB wave-issues, 8 per wave
    #pragma unroll
    for (int i = 0; i < 8; ++i) {
      int nb = (w * 8 + i) * 8;
      int n = nb + lr;
      const char* src = (const char*)Wt + (size_t)n * 512 + k0 * 2
                        + (lc ^ ((n & 7) << 4));
      int dstoff = __builtin_amdgcn_readfirstlane(nb * 128);
      gload_lds16(src, Bs + dstoff);
    }
    __syncthreads();               // compiler drains vmcnt(0) before barrier
    #pragma unroll
    for (int kc = 0; kc < 2; ++kc) {
      const int kb = kc * 64 + blk * 16;
      bf16x8 a[4];
      #pragma unroll
      for (int rf = 0; rf < 4; ++rf)
        a[rf] = *(const bf16x8*)(As + swz(64 * wr + rf * 16 + l15, kb));
      #pragma unroll
      for (int cf = 0; cf < 8; ++cf) {
        bf16x8 b = *(const bf16x8*)(Bs + swz(128 * wc + cf * 16 + l15, kb));
        #pragma unroll
        for (int rf = 0; rf < 4; ++rf)
          acc[rf][cf] = __builtin_amdgcn_mfma_f32_16x16x32_bf16(a[rf], b, acc[rf][cf], 0, 0, 0);
      }
    }
  }

  // epilogue: bias+tanh (+optional dinv row-scale) -> bf16, repack via LDS
  #pragma unroll
  for (int half = 0; half < 2; ++half) {
    __syncthreads();
    if (wr == half) {
      float dvv[4][4];
      #pragma unroll
      for (int rf = 0; rf < 4; ++rf)
        #pragma unroll
        for (int reg = 0; reg < 4; ++reg) {
          int gr = row0 + 64 * half + rf * 16 + 4 * blk + reg;
          dvv[rf][reg] = scale ? scale[gr < M ? gr : M - 1] : 1.0f;
        }
      #pragma unroll
      for (int cf = 0; cf < 8; ++cf) {
        float bcol = bias[128 * wc + cf * 16 + l15];
        #pragma unroll
        for (int rf = 0; rf < 4; ++rf) {
          #pragma unroll
          for (int reg = 0; reg < 4; ++reg) {
            float v = dvv[rf][reg] * tanhf(acc[rf][cf][reg] + bcol);
            Cs[rf * 16 + 4 * blk + reg][128 * wc + cf * 16 + l15] = f2bf(v);
          }
        }
      }
    }
    __syncthreads();
    #pragma unroll
    for (int j = 0; j < 8; ++j) {
      int flat = tid + j * 256;        // 64 rows x 32 chunks
      int r = flat >> 5;
      int c = flat & 31;
      int gr = row0 + half * 64 + r;
      if (gr < M) {
        uint4 v = *(const uint4*)&Cs[r][c * 8];
        *(uint4*)(C + (size_t)gr * UNITS + c * 8) = v;
      }
    }
  }
}

// ============================ fused fc2 + tanh + fc3 (MFMA) -> node scalar ============================

__global__ __launch_bounds__(256) void k_fc23(
    const unsigned short* __restrict__ H,
    const unsigned short* __restrict__ Wt2,
    const float* __restrict__ b2,
    const float* __restrict__ w3, const float* __restrict__ b3,
    float* __restrict__ ns, int M) {
  const int tid = threadIdx.x;
  const int w = tid >> 6;
  const int l = tid & 63;
  const int l15 = l & 15;
  const int blk = l >> 4;
  const int row0 = blockIdx.x * 64 + 16 * w;

  int r = row0 + l15;
  int rc = r < M ? r : M - 1;
  const unsigned short* aPtr = H + (size_t)rc * UNITS + 8 * blk;
  const unsigned short* bPtr = Wt2 + (size_t)l15 * UNITS + 8 * blk;

  f32x4 acc0 = (f32x4){0.f, 0.f, 0.f, 0.f};
  f32x4 acc1 = (f32x4){0.f, 0.f, 0.f, 0.f};
  #pragma unroll
  for (int k0 = 0; k0 < UNITS; k0 += 32) {
    bf16x8 a  = *(const bf16x8*)(aPtr + k0);
    bf16x8 b0 = *(const bf16x8*)(bPtr + k0);
    bf16x8 b1 = *(const bf16x8*)(bPtr + 16 * UNITS + k0);
    acc0 = __builtin_amdgcn_mfma_f32_16x16x32_bf16(a, b0, acc0, 0, 0, 0);
    acc1 = __builtin_amdgcn_mfma_f32_16x16x32_bf16(a, b1, acc1, 0, 0, 0);
  }

  float c0 = b2[l15], c1 = b2[16 + l15];
  float w30 = w3[l15], w31 = w3[16 + l15];
  float b3v = b3[0];
  #pragma unroll
  for (int reg = 0; reg < 4; ++reg) {
    float part = tanhf(acc0[reg] + c0) * w30 + tanhf(acc1[reg] + c1) * w31;
    #pragma unroll
    for (int m = 8; m >= 1; m >>= 1) part += __shfl_xor(part, m);
    int gr = row0 + 4 * blk + reg;
    if (l15 == 0 && gr < M) ns[gr] = part + b3v;
  }
}

// one wave per graph: deterministic segment mean + sigmoid
__global__ __launch_bounds__(64) void k_pool(const float* __restrict__ ns,
                                             const int* __restrict__ starts,
                                             float* __restrict__ out) {
  int g = blockIdx.x;
  int lane = threadIdx.x;
  int s = starts[g], e = starts[g + 1];
  float acc = 0.0f;
  for (int i = s + lane; i < e; i += 64) acc += ns[i];
  #pragma unroll
  for (int m = 32; m >= 1; m >>= 1) acc += __shfl_xor(acc, m);
  if (lane == 0) {
    float mean = acc / fmaxf((float)(e - s), 1.0f);
    out[g] = 1.0f / (1.0f + expf(-mean));
  }
}

// ============================ launch ============================

extern "C" void kernel_launch(void* const* d_in, const int* in_sizes, int n_in,
                              void* d_out, int out_size, void* d_ws, size_t ws_size,
                              hipStream_t stream) {
  const float* x     = (const float*)d_in[0];
  const int*   ei    = (const int*)d_in[1];
  const int*   batch = (const int*)d_in[2];
  const float* Win   = (const float*)d_in[3];
  const float* bin_  = (const float*)d_in[4];
  const float* Ws    = (const float*)d_in[5];
  const float* bs    = (const float*)d_in[6];
  const float* fc1_w = (const float*)d_in[7];
  const float* fc1_b = (const float*)d_in[8];
  const float* fc2_w = (const float*)d_in[9];
  const float* fc2_b = (const float*)d_in[10];
  const float* fc3_w = (const float*)d_in[11];
  const float* fc3_b = (const float*)d_in[12];
  float* out = (float*)d_out;

  char* ws = (char*)d_ws;
  size_t off = 0;
  auto alloc = [&](size_t bytes) {
    size_t o = off;
    off = (off + bytes + 255) & ~(size_t)255;
    return o;
  };
  int*   cnt     = (int*)(ws + alloc(N_NODES * 4));
  int*   fill    = (int*)(ws + alloc(N_NODES * 4));
  int*   row_ptr = (int*)(ws + alloc((N_NODES + 1) * 4));
  float* dinv    = (float*)(ws + alloc(N_NODES * 4));
  int*   col     = (int*)(ws + alloc((size_t)N_EDGES * 4));
  int*   bsum    = (int*)(ws + alloc(NB_SCAN * 4));
  int*   starts  = (int*)(ws + alloc((NGRAPH + 1) * 4));
  float* ns      = (float*)(ws + alloc(N_NODES * 4));
  float* xs      = (float*)(ws + alloc((size_t)N_NODES * IN_FEAT * 4));
  float* p0      = (float*)(ws + alloc((size_t)N_NODES * IN_FEAT * 4));
  unsigned short* Wt   = (unsigned short*)(ws + alloc((size_t)4 * UNITS * UNITS * 2));
  unsigned short* Wt2  = (unsigned short*)(ws + alloc((size_t)32 * UNITS * 2));
  unsigned short* bufA = (unsigned short*)(ws + alloc((size_t)N_NODES * UNITS * 2));
  unsigned short* bufB = (unsigned short*)(ws + alloc((size_t)N_NODES * UNITS * 2));

  hipMemsetAsync(cnt, 0, N_NODES * 4, stream);
  hipMemsetAsync(fill, 0, N_NODES * 4, stream);

  // weights -> bf16 transposed
  k_cvtW<<<(4 * UNITS * UNITS) / 256, 256, 0, stream>>>(Ws, fc1_w, Wt);
  k_cvtW2<<<32, 256, 0, stream>>>(fc2_w, Wt2);

  // CSR build (hierarchical scan) + per-graph segment bounds
  k_count<<<(N_EDGES + 255) / 256, 256, 0, stream>>>(ei, cnt);
  k_bsum<<<NB_SCAN, 256, 0, stream>>>(cnt, bsum);
  k_bscan<<<1, 512, 0, stream>>>(bsum);
  k_scan3<<<NB_SCAN, 256, 0, stream>>>(cnt, bsum, row_ptr);
  k_dinv<<<(N_NODES + 255) / 256, 256, 0, stream>>>(cnt, dinv);
  k_fill<<<(N_EDGES + 255) / 256, 256, 0, stream>>>(ei, row_ptr, fill, col);
  k_bounds<<<3, 256, 0, stream>>>(batch, starts);

  // layer 0: pre-scale x, aggregate 9 f32 feats, GEMM 9->256 + tanh (scaled)
  k_scalex<<<(N_NODES * IN_FEAT + 255) / 256, 256, 0, stream>>>(x, dinv, xs);
  k_agg9<<<(N_NODES + 255) / 256, 256, 0, stream>>>(xs, row_ptr, col, dinv, p0);
  k_gemm9<<<(N_NODES + 31) / 32, 256, 0, stream>>>(p0, Win, bin_, dinv, bufA);

  // layers 1..3: pure-gather aggregate, global_load_lds MFMA GEMM + tanh
  int ggrid = (N_NODES + 127) / 128;
  for (int i = 0; i < 3; ++i) {
    k_agg256<<<(N_NODES + 3) / 4, 256, 0, stream>>>(bufA, row_ptr, col, dinv, bufB);
    const float* sc = (i < 2) ? dinv : nullptr;   // last GCN layer feeds fc1 unscaled
    k_gemm_bf16<<<ggrid, 256, 0, stream>>>(bufB, Wt + (size_t)i * UNITS * UNITS,
                                           bs + (size_t)i * UNITS, sc, bufA, N_NODES);
  }

  // fc1 + tanh (unscaled)
  k_gemm_bf16<<<ggrid, 256, 0, stream>>>(bufA, Wt + (size_t)3 * UNITS * UNITS,
                                         fc1_b, nullptr, bufB, N_NODES);

  // fused fc2 + tanh + fc3 -> per-node scalar
  k_fc23<<<(N_NODES + 63) / 64, 256, 0, stream>>>(bufB, Wt2, fc2_b, fc3_w, fc3_b, ns, N_NODES);

  // segment mean + sigmoid
  k_pool<<<NGRAPH, 64, 0, stream>>>(ns, starts, out);
}

// Round 8
// 715.401 us; speedup vs baseline: 1.4704x; 1.4704x over previous
//
#include <hip/hip_runtime.h>
#include <math.h>

#define N_NODES 100000
#define N_EDGES 1600000
#define UNITS   256
#define NGRAPH  512
#define IN_FEAT 9
#define NB_SCAN ((N_NODES + 255) / 256)   // 391
#define NBUK    ((N_NODES + 255) / 256)   // 391 buckets of 256 dst nodes
#define BCAP    8192                      // bucket capacity (expected ~4092)
#define EPB     16384                     // edges per partition block
#define NPB     ((N_EDGES + EPB - 1) / EPB) // 98

typedef short bf16x8 __attribute__((ext_vector_type(8)));
typedef float f32x4  __attribute__((ext_vector_type(4)));

__device__ __forceinline__ float bflo(unsigned int u) {
  return __builtin_bit_cast(float, u << 16);
}
__device__ __forceinline__ float bfhi(unsigned int u) {
  return __builtin_bit_cast(float, u & 0xffff0000u);
}
__device__ __forceinline__ unsigned short f2bf(float f) {
  unsigned int u = __builtin_bit_cast(unsigned int, f);
  u += 0x7fffu + ((u >> 16) & 1u);   // round-to-nearest-even
  return (unsigned short)(u >> 16);
}

// byte offset into a [rows][64] bf16 LDS tile (128 B rows) with T2 XOR swizzle
__device__ __forceinline__ int swz(int row, int byteInRow) {
  return row * 128 + (byteInRow ^ ((row & 7) << 4));
}

// ============================ bucketed CSR build ============================

// pass 1: partition edges into NBUK buckets (dense appends, block-local hist)
__global__ __launch_bounds__(256) void k_part(const int* __restrict__ ei,
                                              int* __restrict__ bcnt,
                                              uint2* __restrict__ bstore) {
  __shared__ int hist[NBUK];
  __shared__ int base[NBUK];
  int tid = threadIdx.x;
  int e0 = blockIdx.x * EPB;
  for (int i = tid; i < NBUK; i += 256) hist[i] = 0;
  __syncthreads();
  #pragma unroll 4
  for (int j = 0; j < EPB / 256; ++j) {
    int e = e0 + j * 256 + tid;
    if (e < N_EDGES) atomicAdd(&hist[ei[N_EDGES + e] >> 8], 1);
  }
  __syncthreads();
  for (int i = tid; i < NBUK; i += 256) {
    int h = hist[i];
    base[i] = h ? atomicAdd(&bcnt[i], h) : 0;   // reserve contiguous chunk
    hist[i] = 0;                                 // reuse as cursor
  }
  __syncthreads();
  #pragma unroll 4
  for (int j = 0; j < EPB / 256; ++j) {
    int e = e0 + j * 256 + tid;
    if (e < N_EDGES) {
      int s = ei[e];
      int d = ei[N_EDGES + e];
      int b = d >> 8;
      int pos = base[b] + atomicAdd(&hist[b], 1);
      bstore[(size_t)b * BCAP + pos] = make_uint2((unsigned)s, (unsigned)d);
    }
  }
}

// pass 2a: per-bucket degree counts via LDS histogram -> plain stores
__global__ __launch_bounds__(256) void k_cnt(const int* __restrict__ bcnt,
                                             const uint2* __restrict__ bstore,
                                             int* __restrict__ cnt) {
  __shared__ int h[256];
  int b = blockIdx.x, tid = threadIdx.x;
  h[tid] = 0;
  __syncthreads();
  int nE = bcnt[b];
  for (int i = tid; i < nE; i += 256)
    atomicAdd(&h[bstore[(size_t)b * BCAP + i].y & 255], 1);
  __syncthreads();
  int node = b * 256 + tid;
  if (node < N_NODES) cnt[node] = h[tid];
}

// pass 2b: per-bucket col scatter into 16KB XCD-local window (LDS cursors)
__global__ __launch_bounds__(256) void k_colfill(const int* __restrict__ bcnt,
                                                 const uint2* __restrict__ bstore,
                                                 const int* __restrict__ row_ptr,
                                                 int* __restrict__ col) {
  __shared__ int cur[256];
  int b = blockIdx.x, tid = threadIdx.x;
  int node = b * 256 + tid;
  cur[tid] = (node < N_NODES) ? row_ptr[node] : 0;
  __syncthreads();
  int nE = bcnt[b];
  for (int i = tid; i < nE; i += 256) {
    uint2 sd = bstore[(size_t)b * BCAP + i];
    int pos = atomicAdd(&cur[sd.y & 255], 1);
    col[pos] = (int)sd.x;
  }
}

// hierarchical scan: per-256-block sums
__global__ __launch_bounds__(256) void k_bsum(const int* __restrict__ cnt,
                                              int* __restrict__ bsum) {
  __shared__ int wsS[4];
  int b = blockIdx.x, tid = threadIdx.x, lane = tid & 63, w = tid >> 6;
  int idx = b * 256 + tid;
  int s = (idx < N_NODES) ? cnt[idx] : 0;
  #pragma unroll
  for (int m = 32; m >= 1; m >>= 1) s += __shfl_xor(s, m);
  if (lane == 0) wsS[w] = s;
  __syncthreads();
  if (tid == 0) bsum[b] = wsS[0] + wsS[1] + wsS[2] + wsS[3];
}

// exclusive scan of the NB_SCAN block sums (single 512-thread block)
__global__ __launch_bounds__(512) void k_bscan(int* __restrict__ bsum) {
  __shared__ int wsS[8];
  int tid = threadIdx.x, lane = tid & 63, w = tid >> 6;
  int v = (tid < NB_SCAN) ? bsum[tid] : 0;
  int s = v;
  #pragma unroll
  for (int off = 1; off < 64; off <<= 1) {
    int t = __shfl_up(s, off);
    if (lane >= off) s += t;
  }
  if (lane == 63) wsS[w] = s;
  __syncthreads();
  int woff = 0;
  #pragma unroll
  for (int i = 0; i < 8; ++i) woff += (i < w) ? wsS[i] : 0;
  if (tid < NB_SCAN) bsum[tid] = woff + s - v;   // exclusive
}

// block-local exclusive scan + global offset -> row_ptr
__global__ __launch_bounds__(256) void k_scan3(const int* __restrict__ cnt,
                                               const int* __restrict__ bsum,
                                               int* __restrict__ row_ptr) {
  __shared__ int wsS[4];
  int b = blockIdx.x, tid = threadIdx.x, lane = tid & 63, w = tid >> 6;
  int idx = b * 256 + tid;
  int v = (idx < N_NODES) ? cnt[idx] : 0;
  int s = v;
  #pragma unroll
  for (int off = 1; off < 64; off <<= 1) {
    int t = __shfl_up(s, off);
    if (lane >= off) s += t;
  }
  if (lane == 63) wsS[w] = s;
  __syncthreads();
  int woff = 0;
  #pragma unroll
  for (int i = 0; i < 4; ++i) woff += (i < w) ? wsS[i] : 0;
  if (idx < N_NODES) row_ptr[idx] = bsum[b] + woff + s - v;
  if (idx == 0) row_ptr[N_NODES] = N_EDGES;
}

__global__ void k_dinv(const int* __restrict__ cnt, float* __restrict__ dinv) {
  int n = blockIdx.x * blockDim.x + threadIdx.x;
  if (n < N_NODES) dinv[n] = rsqrtf((float)cnt[n] + 1.0f);  // +1 self-loop
}

// segment starts: starts[g] = lower_bound(batch, g); starts[NGRAPH] = N_NODES
__global__ void k_bounds(const int* __restrict__ batch, int* __restrict__ starts) {
  int g = blockIdx.x * blockDim.x + threadIdx.x;
  if (g > NGRAPH) return;
  if (g == NGRAPH) { starts[g] = N_NODES; return; }
  int lo = 0, hi = N_NODES;
  while (lo < hi) { int m = (lo + hi) >> 1; if (batch[m] < g) lo = m + 1; else hi = m; }
  starts[g] = lo;
}

// ============================ Weight transpose/convert ============================

// Wt[m][n][k] = W_m[k][n] as bf16; m = 0..2 -> Ws, m = 3 -> fc1_w
__global__ void k_cvtW(const float* __restrict__ Ws, const float* __restrict__ fc1_w,
                       unsigned short* __restrict__ Wt) {
  int idx = blockIdx.x * 256 + threadIdx.x;   // < 4*256*256
  int m = idx >> 16;
  int r = idx & 65535;
  int n = r >> 8;
  int k = r & 255;
  const float* src = (m < 3) ? (Ws + (size_t)m * 65536) : fc1_w;
  Wt[idx] = f2bf(src[k * 256 + n]);
}

// Wt2[n][k] = fc2_w[k][n] as bf16 (32x256)
__global__ void k_cvtW2(const float* __restrict__ fc2_w, unsigned short* __restrict__ Wt2) {
  int idx = blockIdx.x * 256 + threadIdx.x;   // < 32*256
  int n = idx >> 8;
  int k = idx & 255;
  Wt2[idx] = f2bf(fc2_w[k * 32 + n]);
}

// xs = dinv (x) x  (pre-scaled input features, f32)
__global__ void k_scalex(const float* __restrict__ x, const float* __restrict__ dinv,
                         float* __restrict__ xs) {
  int idx = blockIdx.x * blockDim.x + threadIdx.x;
  if (idx < N_NODES * IN_FEAT) xs[idx] = x[idx] * dinv[idx / IN_FEAT];
}

// ============================ Aggregation ============================

// p0 = dn * (xs[n] + sum xs[src])   (9 features, f32, thread per node)
__global__ void k_agg9(const float* __restrict__ xs, const int* __restrict__ row_ptr,
                       const int* __restrict__ col, const float* __restrict__ dinv,
                       float* __restrict__ p0) {
  int n = blockIdx.x * blockDim.x + threadIdx.x;
  if (n >= N_NODES) return;
  float acc[IN_FEAT];
  #pragma unroll
  for (int j = 0; j < IN_FEAT; ++j) acc[j] = xs[n * IN_FEAT + j];
  int beg = row_ptr[n], end = row_ptr[n + 1];
  for (int e = beg; e < end; ++e) {
    int s = col[e];
    #pragma unroll
    for (int j = 0; j < IN_FEAT; ++j) acc[j] += xs[s * IN_FEAT + j];
  }
  float dn = dinv[n];
  #pragma unroll
  for (int j = 0; j < IN_FEAT; ++j) p0[n * IN_FEAT + j] = dn * acc[j];
}

// p = dn * (hs[n] + sum hs[src])  (hs pre-scaled by dinv; pure gather+add)
__global__ __launch_bounds__(256) void k_agg256(
    const unsigned short* __restrict__ hs, const int* __restrict__ row_ptr,
    const int* __restrict__ col, const float* __restrict__ dinv,
    unsigned short* __restrict__ p) {
  int wid = threadIdx.x >> 6;
  int lane = threadIdx.x & 63;
  int n = blockIdx.x * 4 + wid;
  if (n >= N_NODES) return;
  uint2 q = *(const uint2*)(hs + (size_t)n * UNITS + lane * 4);
  float a0 = bflo(q.x), a1 = bfhi(q.x);
  float a2 = bflo(q.y), a3 = bfhi(q.y);
  int e = row_ptr[n], end = row_ptr[n + 1];
  for (; e + 8 <= end; e += 8) {          // 8 gathers in flight
    int s[8];
    uint2 qq[8];
    #pragma unroll
    for (int j = 0; j < 8; ++j) s[j] = col[e + j];
    #pragma unroll
    for (int j = 0; j < 8; ++j)
      qq[j] = *(const uint2*)(hs + (size_t)s[j] * UNITS + lane * 4);
    #pragma unroll
    for (int j = 0; j < 8; ++j) {
      a0 += bflo(qq[j].x); a1 += bfhi(qq[j].x);
      a2 += bflo(qq[j].y); a3 += bfhi(qq[j].y);
    }
  }
  if (e + 4 <= end) {
    int s[4];
    uint2 qq[4];
    #pragma unroll
    for (int j = 0; j < 4; ++j) s[j] = col[e + j];
    #pragma unroll
    for (int j = 0; j < 4; ++j)
      qq[j] = *(const uint2*)(hs + (size_t)s[j] * UNITS + lane * 4);
    #pragma unroll
    for (int j = 0; j < 4; ++j) {
      a0 += bflo(qq[j].x); a1 += bfhi(qq[j].x);
      a2 += bflo(qq[j].y); a3 += bfhi(qq[j].y);
    }
    e += 4;
  }
  for (; e < end; ++e) {
    int s0 = col[e];
    uint2 q0 = *(const uint2*)(hs + (size_t)s0 * UNITS + lane * 4);
    a0 += bflo(q0.x); a1 += bfhi(q0.x);
    a2 += bflo(q0.y); a3 += bfhi(q0.y);
  }
  float dn = dinv[n];
  uint2 o;
  o.x = (unsigned int)f2bf(dn * a0) | ((unsigned int)f2bf(dn * a1) << 16);
  o.y = (unsigned int)f2bf(dn * a2) | ((unsigned int)f2bf(dn * a3) << 16);
  *(uint2*)(p + (size_t)n * UNITS + lane * 4) = o;
}

// ============================ GEMMs ============================

// h = scale? * tanh(p0 @ Win + bin) -> bf16   [N,9] x [9,256]
__global__ __launch_bounds__(256) void k_gemm9(const float* __restrict__ p0,
                                               const float* __restrict__ Win,
                                               const float* __restrict__ bin,
                                               const float* __restrict__ scale,
                                               unsigned short* __restrict__ h) {
  __shared__ float pS[32][IN_FEAT];
  int tid = threadIdx.x;
  int row0 = blockIdx.x * 32;
  for (int i = tid; i < 32 * IN_FEAT; i += 256) {
    int r = i / IN_FEAT;
    pS[r][i % IN_FEAT] = (row0 + r < N_NODES) ? p0[(size_t)row0 * IN_FEAT + i] : 0.0f;
  }
  float wcol[IN_FEAT];
  #pragma unroll
  for (int k = 0; k < IN_FEAT; ++k) wcol[k] = Win[k * UNITS + tid];
  float b = bin[tid];
  __syncthreads();
  for (int r = 0; r < 32; ++r) {
    int gr = row0 + r;
    if (gr >= N_NODES) break;
    float a = b;
    #pragma unroll
    for (int k = 0; k < IN_FEAT; ++k) a += pS[r][k] * wcol[k];
    float sc = scale ? scale[gr] : 1.0f;
    h[(size_t)gr * UNITS + tid] = f2bf(sc * tanhf(a));
  }
}

// C = scale? * tanh(A @ W + bias) in bf16. A:[M][256], Wt:[256][256] (Wt[n][k]).
// M=64 tile, B-only LDS (reg-staged, swizzled), A direct from global.
// 4 waves 2x2: wave(wr,wc) owns rows 32wr..+31 x cols 128wc..+127.
__global__ __launch_bounds__(256, 4) void k_gemm_bf16(
    const unsigned short* __restrict__ A,
    const unsigned short* __restrict__ Wt,
    const float* __restrict__ bias,
    const float* __restrict__ scale,   // nullable: per-row output scaling (dinv)
    unsigned short* __restrict__ C,
    int M) {
  __shared__ __align__(16) char lds[33792];   // max(Bs 32KB, Cs 33.8KB)
  char* Bs = lds;                             // [256][64] bf16 swizzled
  unsigned short (*Cs)[264] = (unsigned short(*)[264])lds;  // epilogue repack

  const int tid = threadIdx.x;
  const int w = tid >> 6;
  const int l = tid & 63;
  const int l15 = l & 15;
  const int blk = l >> 4;
  const int wr = w >> 1, wc = w & 1;
  const int row0 = blockIdx.x * 64;

  const int sr = tid >> 3;         // B staging: row base 0..31
  const int sc = (tid & 7) * 16;   // byte chunk in 128B row

  const unsigned short* aRow[2];
  #pragma unroll
  for (int rf = 0; rf < 2; ++rf) {
    int gr = row0 + 32 * wr + rf * 16 + l15;
    if (gr >= M) gr = M - 1;       // clamp loads; stores guarded
    aRow[rf] = A + (size_t)gr * UNITS + 8 * blk;
  }

  f32x4 acc[2][8];
  #pragma unroll
  for (int rf = 0; rf < 2; ++rf)
    #pragma unroll
    for (int cf = 0; cf < 8; ++cf) acc[rf][cf] = (f32x4){0.f, 0.f, 0.f, 0.f};

  for (int ks = 0; ks < 4; ++ks) {
    const int k0 = ks * 64;
    if (ks) __syncthreads();
    #pragma unroll
    for (int i = 0; i < 8; ++i) {   // stage B slice [256][64]
      int n = sr + i * 32;
      uint4 v = *(const uint4*)(Wt + (size_t)n * UNITS + k0 + (sc >> 1));
      *(uint4*)(Bs + swz(n, sc)) = v;
    }
    __syncthreads();
    #pragma unroll
    for (int kc = 0; kc < 2; ++kc) {
      bf16x8 a[2];
      #pragma unroll
      for (int rf = 0; rf < 2; ++rf)
        a[rf] = *(const bf16x8*)(aRow[rf] + k0 + kc * 32);
      #pragma unroll
      for (int cf = 0; cf < 8; ++cf) {
        bf16x8 b = *(const bf16x8*)(Bs + swz(128 * wc + cf * 16 + l15, kc * 64 + blk * 16));
        acc[0][cf] = __builtin_amdgcn_mfma_f32_16x16x32_bf16(a[0], b, acc[0][cf], 0, 0, 0);
        acc[1][cf] = __builtin_amdgcn_mfma_f32_16x16x32_bf16(a[1], b, acc[1][cf], 0, 0, 0);
      }
    }
  }

  __syncthreads();                 // Bs free -> reuse as Cs
  float dvv[2][4];
  #pragma unroll
  for (int rf = 0; rf < 2; ++rf)
    #pragma unroll
    for (int reg = 0; reg < 4; ++reg) {
      int gr = row0 + 32 * wr + rf * 16 + 4 * blk + reg;
      dvv[rf][reg] = scale ? scale[gr < M ? gr : M - 1] : 1.0f;
    }
  #pragma unroll
  for (int cf = 0; cf < 8; ++cf) {
    float bcol = bias[128 * wc + cf * 16 + l15];
    #pragma unroll
    for (int rf = 0; rf < 2; ++rf) {
      #pragma unroll
      for (int reg = 0; reg < 4; ++reg) {
        float v = dvv[rf][reg] * tanhf(acc[rf][cf][reg] + bcol);
        Cs[32 * wr + rf * 16 + 4 * blk + reg][128 * wc + cf * 16 + l15] = f2bf(v);
      }
    }
  }
  __syncthreads();
  #pragma unroll
  for (int j = 0; j < 8; ++j) {    // 64 rows x 32 chunks, coalesced 16B stores
    int flat = tid + j * 256;
    int r = flat >> 5;
    int c = flat & 31;
    int gr = row0 + r;
    if (gr < M) {
      uint4 v = *(const uint4*)&Cs[r][c * 8];
      *(uint4*)(C + (size_t)gr * UNITS + c * 8) = v;
    }
  }
}

// ============================ fused fc2 + tanh + fc3 (MFMA) -> node scalar ============================

__global__ __launch_bounds__(256) void k_fc23(
    const unsigned short* __restrict__ H,
    const unsigned short* __restrict__ Wt2,
    const float* __restrict__ b2,
    const float* __restrict__ w3, const float* __restrict__ b3,
    float* __restrict__ ns, int M) {
  const int tid = threadIdx.x;
  const int w = tid >> 6;
  const int l = tid & 63;
  const int l15 = l & 15;
  const int blk = l >> 4;
  const int row0 = blockIdx.x * 64 + 16 * w;

  int r = row0 + l15;
  int rc = r < M ? r : M - 1;
  const unsigned short* aPtr = H + (size_t)rc * UNITS + 8 * blk;
  const unsigned short* bPtr = Wt2 + (size_t)l15 * UNITS + 8 * blk;

  f32x4 acc0 = (f32x4){0.f, 0.f, 0.f, 0.f};
  f32x4 acc1 = (f32x4){0.f, 0.f, 0.f, 0.f};
  #pragma unroll
  for (int k0 = 0; k0 < UNITS; k0 += 32) {
    bf16x8 a  = *(const bf16x8*)(aPtr + k0);
    bf16x8 b0 = *(const bf16x8*)(bPtr + k0);
    bf16x8 b1 = *(const bf16x8*)(bPtr + 16 * UNITS + k0);
    acc0 = __builtin_amdgcn_mfma_f32_16x16x32_bf16(a, b0, acc0, 0, 0, 0);
    acc1 = __builtin_amdgcn_mfma_f32_16x16x32_bf16(a, b1, acc1, 0, 0, 0);
  }

  float c0 = b2[l15], c1 = b2[16 + l15];
  float w30 = w3[l15], w31 = w3[16 + l15];
  float b3v = b3[0];
  #pragma unroll
  for (int reg = 0; reg < 4; ++reg) {
    float part = tanhf(acc0[reg] + c0) * w30 + tanhf(acc1[reg] + c1) * w31;
    #pragma unroll
    for (int m = 8; m >= 1; m >>= 1) part += __shfl_xor(part, m);
    int gr = row0 + 4 * blk + reg;
    if (l15 == 0 && gr < M) ns[gr] = part + b3v;
  }
}

// one wave per graph: deterministic segment mean + sigmoid
__global__ __launch_bounds__(64) void k_pool(const float* __restrict__ ns,
                                             const int* __restrict__ starts,
                                             float* __restrict__ out) {
  int g = blockIdx.x;
  int lane = threadIdx.x;
  int s = starts[g], e = starts[g + 1];
  float acc = 0.0f;
  for (int i = s + lane; i < e; i += 64) acc += ns[i];
  #pragma unroll
  for (int m = 32; m >= 1; m >>= 1) acc += __shfl_xor(acc, m);
  if (lane == 0) {
    float mean = acc / fmaxf((float)(e - s), 1.0f);
    out[g] = 1.0f / (1.0f + expf(-mean));
  }
}

// ============================ launch ============================

extern "C" void kernel_launch(void* const* d_in, const int* in_sizes, int n_in,
                              void* d_out, int out_size, void* d_ws, size_t ws_size,
                              hipStream_t stream) {
  const float* x     = (const float*)d_in[0];
  const int*   ei    = (const int*)d_in[1];
  const int*   batch = (const int*)d_in[2];
  const float* Win   = (const float*)d_in[3];
  const float* bin_  = (const float*)d_in[4];
  const float* Ws    = (const float*)d_in[5];
  const float* bs    = (const float*)d_in[6];
  const float* fc1_w = (const float*)d_in[7];
  const float* fc1_b = (const float*)d_in[8];
  const float* fc2_w = (const float*)d_in[9];
  const float* fc2_b = (const float*)d_in[10];
  const float* fc3_w = (const float*)d_in[11];
  const float* fc3_b = (const float*)d_in[12];
  float* out = (float*)d_out;

  char* ws = (char*)d_ws;
  size_t off = 0;
  auto alloc = [&](size_t bytes) {
    size_t o = off;
    off = (off + bytes + 255) & ~(size_t)255;
    return o;
  };
  int*   cnt     = (int*)(ws + alloc(N_NODES * 4));
  int*   row_ptr = (int*)(ws + alloc((N_NODES + 1) * 4));
  float* dinv    = (float*)(ws + alloc(N_NODES * 4));
  int*   col     = (int*)(ws + alloc((size_t)N_EDGES * 4));
  int*   bsum    = (int*)(ws + alloc(NB_SCAN * 4));
  int*   bcnt    = (int*)(ws + alloc(NBUK * 4));
  uint2* bstore  = (uint2*)(ws + alloc((size_t)NBUK * BCAP * 8));
  int*   starts  = (int*)(ws + alloc((NGRAPH + 1) * 4));
  float* ns      = (float*)(ws + alloc(N_NODES * 4));
  float* xs      = (float*)(ws + alloc((size_t)N_NODES * IN_FEAT * 4));
  float* p0      = (float*)(ws + alloc((size_t)N_NODES * IN_FEAT * 4));
  unsigned short* Wt   = (unsigned short*)(ws + alloc((size_t)4 * UNITS * UNITS * 2));
  unsigned short* Wt2  = (unsigned short*)(ws + alloc((size_t)32 * UNITS * 2));
  unsigned short* bufA = (unsigned short*)(ws + alloc((size_t)N_NODES * UNITS * 2));
  unsigned short* bufB = (unsigned short*)(ws + alloc((size_t)N_NODES * UNITS * 2));

  hipMemsetAsync(bcnt, 0, NBUK * 4, stream);

  // weights -> bf16 transposed
  k_cvtW<<<(4 * UNITS * UNITS) / 256, 256, 0, stream>>>(Ws, fc1_w, Wt);
  k_cvtW2<<<32, 256, 0, stream>>>(fc2_w, Wt2);

  // bucketed CSR build + hierarchical scan + per-graph segment bounds
  k_part<<<NPB, 256, 0, stream>>>(ei, bcnt, bstore);
  k_cnt<<<NBUK, 256, 0, stream>>>(bcnt, bstore, cnt);
  k_bsum<<<NB_SCAN, 256, 0, stream>>>(cnt, bsum);
  k_bscan<<<1, 512, 0, stream>>>(bsum);
  k_scan3<<<NB_SCAN, 256, 0, stream>>>(cnt, bsum, row_ptr);
  k_dinv<<<(N_NODES + 255) / 256, 256, 0, stream>>>(cnt, dinv);
  k_colfill<<<NBUK, 256, 0, stream>>>(bcnt, bstore, row_ptr, col);
  k_bounds<<<3, 256, 0, stream>>>(batch, starts);

  // layer 0: pre-scale x, aggregate 9 f32 feats, GEMM 9->256 + tanh (scaled)
  k_scalex<<<(N_NODES * IN_FEAT + 255) / 256, 256, 0, stream>>>(x, dinv, xs);
  k_agg9<<<(N_NODES + 255) / 256, 256, 0, stream>>>(xs, row_ptr, col, dinv, p0);
  k_gemm9<<<(N_NODES + 31) / 32, 256, 0, stream>>>(p0, Win, bin_, dinv, bufA);

  // layers 1..3: pure-gather aggregate, M=64-tile MFMA GEMM + tanh
  int ggrid = (N_NODES + 63) / 64;
  for (int i = 0; i < 3; ++i) {
    k_agg256<<<(N_NODES + 3) / 4, 256, 0, stream>>>(bufA, row_ptr, col, dinv, bufB);
    const float* sc = (i < 2) ? dinv : nullptr;   // last GCN layer feeds fc1 unscaled
    k_gemm_bf16<<<ggrid, 256, 0, stream>>>(bufB, Wt + (size_t)i * UNITS * UNITS,
                                           bs + (size_t)i * UNITS, sc, bufA, N_NODES);
  }

  // fc1 + tanh (unscaled)
  k_gemm_bf16<<<ggrid, 256, 0, stream>>>(bufA, Wt + (size_t)3 * UNITS * UNITS,
                                         fc1_b, nullptr, bufB, N_NODES);

  // fused fc2 + tanh + fc3 -> per-node scalar
  k_fc23<<<(N_NODES + 63) / 64, 256, 0, stream>>>(bufB, Wt2, fc2_b, fc3_w, fc3_b, ns, N_NODES);

  // segment mean + sigmoid
  k_pool<<<NGRAPH, 64, 0, stream>>>(ns, starts, out);
}

// Round 9
// 561.902 us; speedup vs baseline: 1.8721x; 1.2732x over previous
//
#include <hip/hip_runtime.h>
#include <math.h>

#define N_NODES 100000
#define N_EDGES 1600000
#define UNITS   256
#define NGRAPH  512
#define IN_FEAT 9
#define NB_SCAN ((N_NODES + 255) / 256)   // 391
#define NBUK    ((N_NODES + 255) / 256)   // 391 buckets of 256 dst nodes
#define BCAP    8192                      // bucket capacity (expected ~4092)
#define EPB     16384                     // edges per partition block
#define NPB     ((N_EDGES + EPB - 1) / EPB) // 98

typedef short bf16x8 __attribute__((ext_vector_type(8)));
typedef float f32x4  __attribute__((ext_vector_type(4)));
typedef float f32x2  __attribute__((ext_vector_type(2)));

__device__ __forceinline__ float bflo(unsigned int u) {
  return __builtin_bit_cast(float, u << 16);
}
__device__ __forceinline__ float bfhi(unsigned int u) {
  return __builtin_bit_cast(float, u & 0xffff0000u);
}
__device__ __forceinline__ unsigned short f2bf(float f) {
  unsigned int u = __builtin_bit_cast(unsigned int, f);
  u += 0x7fffu + ((u >> 16) & 1u);   // round-to-nearest-even
  return (unsigned short)(u >> 16);
}

// byte offset into a [rows][64] bf16 LDS tile (128 B rows) with T2 XOR swizzle
__device__ __forceinline__ int swz(int row, int byteInRow) {
  return row * 128 + (byteInRow ^ ((row & 7) << 4));
}

// ============================ bucketed CSR build ============================

__global__ __launch_bounds__(256) void k_part(const int* __restrict__ ei,
                                              int* __restrict__ bcnt,
                                              uint2* __restrict__ bstore) {
  __shared__ int hist[NBUK];
  __shared__ int base[NBUK];
  int tid = threadIdx.x;
  int e0 = blockIdx.x * EPB;
  for (int i = tid; i < NBUK; i += 256) hist[i] = 0;
  __syncthreads();
  #pragma unroll 4
  for (int j = 0; j < EPB / 256; ++j) {
    int e = e0 + j * 256 + tid;
    if (e < N_EDGES) atomicAdd(&hist[ei[N_EDGES + e] >> 8], 1);
  }
  __syncthreads();
  for (int i = tid; i < NBUK; i += 256) {
    int h = hist[i];
    base[i] = h ? atomicAdd(&bcnt[i], h) : 0;   // reserve contiguous chunk
    hist[i] = 0;                                 // reuse as cursor
  }
  __syncthreads();
  #pragma unroll 4
  for (int j = 0; j < EPB / 256; ++j) {
    int e = e0 + j * 256 + tid;
    if (e < N_EDGES) {
      int s = ei[e];
      int d = ei[N_EDGES + e];
      int b = d >> 8;
      int pos = base[b] + atomicAdd(&hist[b], 1);
      bstore[(size_t)b * BCAP + pos] = make_uint2((unsigned)s, (unsigned)d);
    }
  }
}

__global__ __launch_bounds__(256) void k_cnt(const int* __restrict__ bcnt,
                                             const uint2* __restrict__ bstore,
                                             int* __restrict__ cnt) {
  __shared__ int h[256];
  int b = blockIdx.x, tid = threadIdx.x;
  h[tid] = 0;
  __syncthreads();
  int nE = bcnt[b];
  for (int i = tid; i < nE; i += 256)
    atomicAdd(&h[bstore[(size_t)b * BCAP + i].y & 255], 1);
  __syncthreads();
  int node = b * 256 + tid;
  if (node < N_NODES) cnt[node] = h[tid];
}

__global__ __launch_bounds__(256) void k_colfill(const int* __restrict__ bcnt,
                                                 const uint2* __restrict__ bstore,
                                                 const int* __restrict__ row_ptr,
                                                 int* __restrict__ col) {
  __shared__ int cur[256];
  int b = blockIdx.x, tid = threadIdx.x;
  int node = b * 256 + tid;
  cur[tid] = (node < N_NODES) ? row_ptr[node] : 0;
  __syncthreads();
  int nE = bcnt[b];
  for (int i = tid; i < nE; i += 256) {
    uint2 sd = bstore[(size_t)b * BCAP + i];
    int pos = atomicAdd(&cur[sd.y & 255], 1);
    col[pos] = (int)sd.x;
  }
}

__global__ __launch_bounds__(256) void k_bsum(const int* __restrict__ cnt,
                                              int* __restrict__ bsum) {
  __shared__ int wsS[4];
  int b = blockIdx.x, tid = threadIdx.x, lane = tid & 63, w = tid >> 6;
  int idx = b * 256 + tid;
  int s = (idx < N_NODES) ? cnt[idx] : 0;
  #pragma unroll
  for (int m = 32; m >= 1; m >>= 1) s += __shfl_xor(s, m);
  if (lane == 0) wsS[w] = s;
  __syncthreads();
  if (tid == 0) bsum[b] = wsS[0] + wsS[1] + wsS[2] + wsS[3];
}

__global__ __launch_bounds__(512) void k_bscan(int* __restrict__ bsum) {
  __shared__ int wsS[8];
  int tid = threadIdx.x, lane = tid & 63, w = tid >> 6;
  int v = (tid < NB_SCAN) ? bsum[tid] : 0;
  int s = v;
  #pragma unroll
  for (int off = 1; off < 64; off <<= 1) {
    int t = __shfl_up(s, off);
    if (lane >= off) s += t;
  }
  if (lane == 63) wsS[w] = s;
  __syncthreads();
  int woff = 0;
  #pragma unroll
  for (int i = 0; i < 8; ++i) woff += (i < w) ? wsS[i] : 0;
  if (tid < NB_SCAN) bsum[tid] = woff + s - v;   // exclusive
}

__global__ __launch_bounds__(256) void k_scan3(const int* __restrict__ cnt,
                                               const int* __restrict__ bsum,
                                               int* __restrict__ row_ptr) {
  __shared__ int wsS[4];
  int b = blockIdx.x, tid = threadIdx.x, lane = tid & 63, w = tid >> 6;
  int idx = b * 256 + tid;
  int v = (idx < N_NODES) ? cnt[idx] : 0;
  int s = v;
  #pragma unroll
  for (int off = 1; off < 64; off <<= 1) {
    int t = __shfl_up(s, off);
    if (lane >= off) s += t;
  }
  if (lane == 63) wsS[w] = s;
  __syncthreads();
  int woff = 0;
  #pragma unroll
  for (int i = 0; i < 4; ++i) woff += (i < w) ? wsS[i] : 0;
  if (idx < N_NODES) row_ptr[idx] = bsum[b] + woff + s - v;
  if (idx == 0) row_ptr[N_NODES] = N_EDGES;
}

__global__ void k_dinv(const int* __restrict__ cnt, float* __restrict__ dinv) {
  int n = blockIdx.x * blockDim.x + threadIdx.x;
  if (n < N_NODES) dinv[n] = rsqrtf((float)cnt[n] + 1.0f);  // +1 self-loop
}

__global__ void k_bounds(const int* __restrict__ batch, int* __restrict__ starts) {
  int g = blockIdx.x * blockDim.x + threadIdx.x;
  if (g > NGRAPH) return;
  if (g == NGRAPH) { starts[g] = N_NODES; return; }
  int lo = 0, hi = N_NODES;
  while (lo < hi) { int m = (lo + hi) >> 1; if (batch[m] < g) lo = m + 1; else hi = m; }
  starts[g] = lo;
}

// ============================ Weight transpose/convert ============================

__global__ void k_cvtW(const float* __restrict__ Ws, const float* __restrict__ fc1_w,
                       unsigned short* __restrict__ Wt) {
  int idx = blockIdx.x * 256 + threadIdx.x;   // < 4*256*256
  int m = idx >> 16;
  int r = idx & 65535;
  int n = r >> 8;
  int k = r & 255;
  const float* src = (m < 3) ? (Ws + (size_t)m * 65536) : fc1_w;
  Wt[idx] = f2bf(src[k * 256 + n]);
}

__global__ void k_cvtW2(const float* __restrict__ fc2_w, unsigned short* __restrict__ Wt2) {
  int idx = blockIdx.x * 256 + threadIdx.x;   // < 32*256
  int n = idx >> 8;
  int k = idx & 255;
  Wt2[idx] = f2bf(fc2_w[k * 32 + n]);
}

__global__ void k_scalex(const float* __restrict__ x, const float* __restrict__ dinv,
                         float* __restrict__ xs) {
  int idx = blockIdx.x * blockDim.x + threadIdx.x;
  if (idx < N_NODES * IN_FEAT) xs[idx] = x[idx] * dinv[idx / IN_FEAT];
}

// ============================ Aggregation ============================

__global__ void k_agg9(const float* __restrict__ xs, const int* __restrict__ row_ptr,
                       const int* __restrict__ col, const float* __restrict__ dinv,
                       float* __restrict__ p0) {
  int n = blockIdx.x * blockDim.x + threadIdx.x;
  if (n >= N_NODES) return;
  float acc[IN_FEAT];
  #pragma unroll
  for (int j = 0; j < IN_FEAT; ++j) acc[j] = xs[n * IN_FEAT + j];
  int beg = row_ptr[n], end = row_ptr[n + 1];
  for (int e = beg; e < end; ++e) {
    int s = col[e];
    #pragma unroll
    for (int j = 0; j < IN_FEAT; ++j) acc[j] += xs[s * IN_FEAT + j];
  }
  float dn = dinv[n];
  #pragma unroll
  for (int j = 0; j < IN_FEAT; ++j) p0[n * IN_FEAT + j] = dn * acc[j];
}

// p = dn * (hs[n] + sum hs[src]) ; hs stored fp8 e4m3 (pre-scaled by dinv).
// one wave per node, 4 feats/lane (1 uint = 4 fp8), f32 acc, 8/4/1 pipelining.
__global__ __launch_bounds__(256) void k_agg256(
    const unsigned int* __restrict__ hs8,   // [N][64] words
    const int* __restrict__ row_ptr, const int* __restrict__ col,
    const float* __restrict__ dinv, unsigned short* __restrict__ p) {
  int wid = threadIdx.x >> 6;
  int lane = threadIdx.x & 63;
  int n = blockIdx.x * 4 + wid;
  if (n >= N_NODES) return;
  unsigned int q = hs8[(size_t)n * 64 + lane];
  f32x2 lo = __builtin_amdgcn_cvt_pk_f32_fp8(q, false);
  f32x2 hi = __builtin_amdgcn_cvt_pk_f32_fp8(q, true);
  float a0 = lo[0], a1 = lo[1], a2 = hi[0], a3 = hi[1];
  int e = row_ptr[n], end = row_ptr[n + 1];
  for (; e + 8 <= end; e += 8) {          // 8 gathers in flight
    int s[8];
    unsigned int qq[8];
    #pragma unroll
    for (int j = 0; j < 8; ++j) s[j] = col[e + j];
    #pragma unroll
    for (int j = 0; j < 8; ++j) qq[j] = hs8[(size_t)s[j] * 64 + lane];
    #pragma unroll
    for (int j = 0; j < 8; ++j) {
      f32x2 l2 = __builtin_amdgcn_cvt_pk_f32_fp8(qq[j], false);
      f32x2 h2 = __builtin_amdgcn_cvt_pk_f32_fp8(qq[j], true);
      a0 += l2[0]; a1 += l2[1]; a2 += h2[0]; a3 += h2[1];
    }
  }
  if (e + 4 <= end) {
    int s[4];
    unsigned int qq[4];
    #pragma unroll
    for (int j = 0; j < 4; ++j) s[j] = col[e + j];
    #pragma unroll
    for (int j = 0; j < 4; ++j) qq[j] = hs8[(size_t)s[j] * 64 + lane];
    #pragma unroll
    for (int j = 0; j < 4; ++j) {
      f32x2 l2 = __builtin_amdgcn_cvt_pk_f32_fp8(qq[j], false);
      f32x2 h2 = __builtin_amdgcn_cvt_pk_f32_fp8(qq[j], true);
      a0 += l2[0]; a1 += l2[1]; a2 += h2[0]; a3 += h2[1];
    }
    e += 4;
  }
  for (; e < end; ++e) {
    unsigned int q0 = hs8[(size_t)col[e] * 64 + lane];
    f32x2 l2 = __builtin_amdgcn_cvt_pk_f32_fp8(q0, false);
    f32x2 h2 = __builtin_amdgcn_cvt_pk_f32_fp8(q0, true);
    a0 += l2[0]; a1 += l2[1]; a2 += h2[0]; a3 += h2[1];
  }
  float dn = dinv[n];
  uint2 o;
  o.x = (unsigned int)f2bf(dn * a0) | ((unsigned int)f2bf(dn * a1) << 16);
  o.y = (unsigned int)f2bf(dn * a2) | ((unsigned int)f2bf(dn * a3) << 16);
  *(uint2*)(p + (size_t)n * UNITS + lane * 4) = o;
}

// ============================ GEMMs ============================

// h8 = fp8( dinv * tanh(p0 @ Win + bin) )   [N,9] x [9,256]
__global__ __launch_bounds__(256) void k_gemm9(const float* __restrict__ p0,
                                               const float* __restrict__ Win,
                                               const float* __restrict__ bin,
                                               const float* __restrict__ scale,
                                               unsigned char* __restrict__ h8) {
  __shared__ float pS[32][IN_FEAT];
  int tid = threadIdx.x;
  int row0 = blockIdx.x * 32;
  for (int i = tid; i < 32 * IN_FEAT; i += 256) {
    int r = i / IN_FEAT;
    pS[r][i % IN_FEAT] = (row0 + r < N_NODES) ? p0[(size_t)row0 * IN_FEAT + i] : 0.0f;
  }
  float wcol[IN_FEAT];
  #pragma unroll
  for (int k = 0; k < IN_FEAT; ++k) wcol[k] = Win[k * UNITS + tid];
  float b = bin[tid];
  __syncthreads();
  for (int r = 0; r < 32; ++r) {
    int gr = row0 + r;
    if (gr >= N_NODES) break;
    float a = b;
    #pragma unroll
    for (int k = 0; k < IN_FEAT; ++k) a += pS[r][k] * wcol[k];
    float v = scale[gr] * tanhf(a);
    float vn = __shfl_xor(v, 1);
    if ((tid & 1) == 0) {
      unsigned int pk = __builtin_amdgcn_cvt_pk_fp8_f32(v, vn, 0, false);
      *(unsigned short*)(h8 + (size_t)gr * UNITS + tid) = (unsigned short)pk;
    }
  }
}

// C = scale? * tanh(A @ W + bias); output bf16 or fp8 (out_fp8 flag).
// A:[M][256] bf16, Wt:[256][256] bf16 (Wt[n][k]).
// M=64 tile, B-only LDS (reg-staged, swizzled), A direct from global.
__global__ __launch_bounds__(256, 4) void k_gemm_bf16(
    const unsigned short* __restrict__ A,
    const unsigned short* __restrict__ Wt,
    const float* __restrict__ bias,
    const float* __restrict__ scale,   // nullable: per-row output scaling (dinv)
    void* __restrict__ Cout, int out_fp8,
    int M) {
  __shared__ __align__(16) char lds[33792];   // max(Bs 32KB, Cs 33.8KB)
  char* Bs = lds;                             // [256][64] bf16 swizzled
  unsigned short (*Cs)[264] = (unsigned short(*)[264])lds;  // epilogue repack

  const int tid = threadIdx.x;
  const int w = tid >> 6;
  const int l = tid & 63;
  const int l15 = l & 15;
  const int blk = l >> 4;
  const int wr = w >> 1, wc = w & 1;
  const int row0 = blockIdx.x * 64;

  const int sr = tid >> 3;         // B staging: row base 0..31
  const int sc = (tid & 7) * 16;   // byte chunk in 128B row

  const unsigned short* aRow[2];
  #pragma unroll
  for (int rf = 0; rf < 2; ++rf) {
    int gr = row0 + 32 * wr + rf * 16 + l15;
    if (gr >= M) gr = M - 1;       // clamp loads; stores guarded
    aRow[rf] = A + (size_t)gr * UNITS + 8 * blk;
  }

  f32x4 acc[2][8];
  #pragma unroll
  for (int rf = 0; rf < 2; ++rf)
    #pragma unroll
    for (int cf = 0; cf < 8; ++cf) acc[rf][cf] = (f32x4){0.f, 0.f, 0.f, 0.f};

  for (int ks = 0; ks < 4; ++ks) {
    const int k0 = ks * 64;
    if (ks) __syncthreads();
    #pragma unroll
    for (int i = 0; i < 8; ++i) {   // stage B slice [256][64]
      int n = sr + i * 32;
      uint4 v = *(const uint4*)(Wt + (size_t)n * UNITS + k0 + (sc >> 1));
      *(uint4*)(Bs + swz(n, sc)) = v;
    }
    __syncthreads();
    #pragma unroll
    for (int kc = 0; kc < 2; ++kc) {
      bf16x8 a[2];
      #pragma unroll
      for (int rf = 0; rf < 2; ++rf)
        a[rf] = *(const bf16x8*)(aRow[rf] + k0 + kc * 32);
      #pragma unroll
      for (int cf = 0; cf < 8; ++cf) {
        bf16x8 b = *(const bf16x8*)(Bs + swz(128 * wc + cf * 16 + l15, kc * 64 + blk * 16));
        acc[0][cf] = __builtin_amdgcn_mfma_f32_16x16x32_bf16(a[0], b, acc[0][cf], 0, 0, 0);
        acc[1][cf] = __builtin_amdgcn_mfma_f32_16x16x32_bf16(a[1], b, acc[1][cf], 0, 0, 0);
      }
    }
  }

  __syncthreads();                 // Bs free -> reuse as Cs
  float dvv[2][4];
  #pragma unroll
  for (int rf = 0; rf < 2; ++rf)
    #pragma unroll
    for (int reg = 0; reg < 4; ++reg) {
      int gr = row0 + 32 * wr + rf * 16 + 4 * blk + reg;
      dvv[rf][reg] = scale ? scale[gr < M ? gr : M - 1] : 1.0f;
    }
  #pragma unroll
  for (int cf = 0; cf < 8; ++cf) {
    float bcol = bias[128 * wc + cf * 16 + l15];
    #pragma unroll
    for (int rf = 0; rf < 2; ++rf) {
      #pragma unroll
      for (int reg = 0; reg < 4; ++reg) {
        float v = dvv[rf][reg] * tanhf(acc[rf][cf][reg] + bcol);
        Cs[32 * wr + rf * 16 + 4 * blk + reg][128 * wc + cf * 16 + l15] = f2bf(v);
      }
    }
  }
  __syncthreads();
  if (out_fp8) {
    unsigned char* C8 = (unsigned char*)Cout;
    #pragma unroll
    for (int j = 0; j < 8; ++j) {  // 64 rows x 32 chunks of 8 fp8 (8B)
      int flat = tid + j * 256;
      int r = flat >> 5;
      int c = flat & 31;
      int gr = row0 + r;
      if (gr < M) {
        uint4 v = *(const uint4*)&Cs[r][c * 8];
        uint2 u;
        u.x = __builtin_amdgcn_cvt_pk_fp8_f32(bflo(v.x), bfhi(v.x), 0, false);
        u.x = __builtin_amdgcn_cvt_pk_fp8_f32(bflo(v.y), bfhi(v.y), u.x, true);
        u.y = __builtin_amdgcn_cvt_pk_fp8_f32(bflo(v.z), bfhi(v.z), 0, false);
        u.y = __builtin_amdgcn_cvt_pk_fp8_f32(bflo(v.w), bfhi(v.w), u.y, true);
        *(uint2*)(C8 + (size_t)gr * UNITS + c * 8) = u;
      }
    }
  } else {
    unsigned short* C = (unsigned short*)Cout;
    #pragma unroll
    for (int j = 0; j < 8; ++j) {  // 64 rows x 32 chunks of 8 bf16 (16B)
      int flat = tid + j * 256;
      int r = flat >> 5;
      int c = flat & 31;
      int gr = row0 + r;
      if (gr < M) {
        uint4 v = *(const uint4*)&Cs[r][c * 8];
        *(uint4*)(C + (size_t)gr * UNITS + c * 8) = v;
      }
    }
  }
}

// ============================ fused fc2 + tanh + fc3 (MFMA) -> node scalar ============================

__global__ __launch_bounds__(256) void k_fc23(
    const unsigned short* __restrict__ H,
    const unsigned short* __restrict__ Wt2,
    const float* __restrict__ b2,
    const float* __restrict__ w3, const float* __restrict__ b3,
    float* __restrict__ ns, int M) {
  const int tid = threadIdx.x;
  const int w = tid >> 6;
  const int l = tid & 63;
  const int l15 = l & 15;
  const int blk = l >> 4;
  const int row0 = blockIdx.x * 64 + 16 * w;

  int r = row0 + l15;
  int rc = r < M ? r : M - 1;
  const unsigned short* aPtr = H + (size_t)rc * UNITS + 8 * blk;
  const unsigned short* bPtr = Wt2 + (size_t)l15 * UNITS + 8 * blk;

  f32x4 acc0 = (f32x4){0.f, 0.f, 0.f, 0.f};
  f32x4 acc1 = (f32x4){0.f, 0.f, 0.f, 0.f};
  #pragma unroll
  for (int k0 = 0; k0 < UNITS; k0 += 32) {
    bf16x8 a  = *(const bf16x8*)(aPtr + k0);
    bf16x8 b0 = *(const bf16x8*)(bPtr + k0);
    bf16x8 b1 = *(const bf16x8*)(bPtr + 16 * UNITS + k0);
    acc0 = __builtin_amdgcn_mfma_f32_16x16x32_bf16(a, b0, acc0, 0, 0, 0);
    acc1 = __builtin_amdgcn_mfma_f32_16x16x32_bf16(a, b1, acc1, 0, 0, 0);
  }

  float c0 = b2[l15], c1 = b2[16 + l15];
  float w30 = w3[l15], w31 = w3[16 + l15];
  float b3v = b3[0];
  #pragma unroll
  for (int reg = 0; reg < 4; ++reg) {
    float part = tanhf(acc0[reg] + c0) * w30 + tanhf(acc1[reg] + c1) * w31;
    #pragma unroll
    for (int m = 8; m >= 1; m >>= 1) part += __shfl_xor(part, m);
    int gr = row0 + 4 * blk + reg;
    if (l15 == 0 && gr < M) ns[gr] = part + b3v;
  }
}

// one wave per graph: deterministic segment mean + sigmoid
__global__ __launch_bounds__(64) void k_pool(const float* __restrict__ ns,
                                             const int* __restrict__ starts,
                                             float* __restrict__ out) {
  int g = blockIdx.x;
  int lane = threadIdx.x;
  int s = starts[g], e = starts[g + 1];
  float acc = 0.0f;
  for (int i = s + lane; i < e; i += 64) acc += ns[i];
  #pragma unroll
  for (int m = 32; m >= 1; m >>= 1) acc += __shfl_xor(acc, m);
  if (lane == 0) {
    float mean = acc / fmaxf((float)(e - s), 1.0f);
    out[g] = 1.0f / (1.0f + expf(-mean));
  }
}

// ============================ launch ============================

extern "C" void kernel_launch(void* const* d_in, const int* in_sizes, int n_in,
                              void* d_out, int out_size, void* d_ws, size_t ws_size,
                              hipStream_t stream) {
  const float* x     = (const float*)d_in[0];
  const int*   ei    = (const int*)d_in[1];
  const int*   batch = (const int*)d_in[2];
  const float* Win   = (const float*)d_in[3];
  const float* bin_  = (const float*)d_in[4];
  const float* Ws    = (const float*)d_in[5];
  const float* bs    = (const float*)d_in[6];
  const float* fc1_w = (const float*)d_in[7];
  const float* fc1_b = (const float*)d_in[8];
  const float* fc2_w = (const float*)d_in[9];
  const float* fc2_b = (const float*)d_in[10];
  const float* fc3_w = (const float*)d_in[11];
  const float* fc3_b = (const float*)d_in[12];
  float* out = (float*)d_out;

  char* ws = (char*)d_ws;
  size_t off = 0;
  auto alloc = [&](size_t bytes) {
    size_t o = off;
    off = (off + bytes + 255) & ~(size_t)255;
    return o;
  };
  int*   cnt     = (int*)(ws + alloc(N_NODES * 4));
  int*   row_ptr = (int*)(ws + alloc((N_NODES + 1) * 4));
  float* dinv    = (float*)(ws + alloc(N_NODES * 4));
  int*   col     = (int*)(ws + alloc((size_t)N_EDGES * 4));
  int*   bsum    = (int*)(ws + alloc(NB_SCAN * 4));
  int*   bcnt    = (int*)(ws + alloc(NBUK * 4));
  uint2* bstore  = (uint2*)(ws + alloc((size_t)NBUK * BCAP * 8));
  int*   starts  = (int*)(ws + alloc((NGRAPH + 1) * 4));
  float* ns      = (float*)(ws + alloc(N_NODES * 4));
  float* xs      = (float*)(ws + alloc((size_t)N_NODES * IN_FEAT * 4));
  float* p0      = (float*)(ws + alloc((size_t)N_NODES * IN_FEAT * 4));
  unsigned short* Wt   = (unsigned short*)(ws + alloc((size_t)4 * UNITS * UNITS * 2));
  unsigned short* Wt2  = (unsigned short*)(ws + alloc((size_t)32 * UNITS * 2));
  unsigned char*  h8a  = (unsigned char*)(ws + alloc((size_t)N_NODES * UNITS));
  unsigned char*  h8b  = (unsigned char*)(ws + alloc((size_t)N_NODES * UNITS));
  unsigned short* pbf  = (unsigned short*)(ws + alloc((size_t)N_NODES * UNITS * 2));
  unsigned short* hbf  = (unsigned short*)(ws + alloc((size_t)N_NODES * UNITS * 2));

  hipMemsetAsync(bcnt, 0, NBUK * 4, stream);

  // weights -> bf16 transposed
  k_cvtW<<<(4 * UNITS * UNITS) / 256, 256, 0, stream>>>(Ws, fc1_w, Wt);
  k_cvtW2<<<32, 256, 0, stream>>>(fc2_w, Wt2);

  // bucketed CSR build + hierarchical scan + per-graph segment bounds
  k_part<<<NPB, 256, 0, stream>>>(ei, bcnt, bstore);
  k_cnt<<<NBUK, 256, 0, stream>>>(bcnt, bstore, cnt);
  k_bsum<<<NB_SCAN, 256, 0, stream>>>(cnt, bsum);
  k_bscan<<<1, 512, 0, stream>>>(bsum);
  k_scan3<<<NB_SCAN, 256, 0, stream>>>(cnt, bsum, row_ptr);
  k_dinv<<<(N_NODES + 255) / 256, 256, 0, stream>>>(cnt, dinv);
  k_colfill<<<NBUK, 256, 0, stream>>>(bcnt, bstore, row_ptr, col);
  k_bounds<<<3, 256, 0, stream>>>(batch, starts);

  // layer 0: pre-scale x, aggregate 9 f32 feats, GEMM 9->256 + tanh -> fp8 (scaled)
  k_scalex<<<(N_NODES * IN_FEAT + 255) / 256, 256, 0, stream>>>(x, dinv, xs);
  k_agg9<<<(N_NODES + 255) / 256, 256, 0, stream>>>(xs, row_ptr, col, dinv, p0);
  k_gemm9<<<(N_NODES + 31) / 32, 256, 0, stream>>>(p0, Win, bin_, dinv, h8a);

  // layers 1..3: fp8-gather aggregate, MFMA GEMM + tanh
  int ggrid = (N_NODES + 63) / 64;
  // i=0: agg(h8a)->pbf ; gemm -> h8b (fp8, scaled)
  k_agg256<<<(N_NODES + 3) / 4, 256, 0, stream>>>((const unsigned int*)h8a, row_ptr, col, dinv, pbf);
  k_gemm_bf16<<<ggrid, 256, 0, stream>>>(pbf, Wt + (size_t)0 * UNITS * UNITS,
                                         bs + (size_t)0 * UNITS, dinv, h8b, 1, N_NODES);
  // i=1: agg(h8b)->pbf ; gemm -> h8a (fp8, scaled)
  k_agg256<<<(N_NODES + 3) / 4, 256, 0, stream>>>((const unsigned int*)h8b, row_ptr, col, dinv, pbf);
  k_gemm_bf16<<<ggrid, 256, 0, stream>>>(pbf, Wt + (size_t)1 * UNITS * UNITS,
                                         bs + (size_t)1 * UNITS, dinv, h8a, 1, N_NODES);
  // i=2: agg(h8a)->pbf ; gemm -> hbf (bf16, unscaled; feeds fc1)
  k_agg256<<<(N_NODES + 3) / 4, 256, 0, stream>>>((const unsigned int*)h8a, row_ptr, col, dinv, pbf);
  k_gemm_bf16<<<ggrid, 256, 0, stream>>>(pbf, Wt + (size_t)2 * UNITS * UNITS,
                                         bs + (size_t)2 * UNITS, nullptr, hbf, 0, N_NODES);

  // fc1 + tanh (bf16, unscaled)
  k_gemm_bf16<<<ggrid, 256, 0, stream>>>(hbf, Wt + (size_t)3 * UNITS * UNITS,
                                         fc1_b, nullptr, pbf, 0, N_NODES);

  // fused fc2 + tanh + fc3 -> per-node scalar
  k_fc23<<<(N_NODES + 63) / 64, 256, 0, stream>>>(pbf, Wt2, fc2_b, fc3_w, fc3_b, ns, N_NODES);

  // segment mean + sigmoid
  k_pool<<<NGRAPH, 64, 0, stream>>>(ns, starts, out);
}